// Round 3
// baseline (81.897 us; speedup 1.0000x reference)
//
#include <hip/hip_runtime.h>

#define NEG_SLOPE 0.2f

// Native fire-and-forget fp32 atomic (global_atomic_add_f32, no CAS loop).
__device__ __forceinline__ void atomAddF(float* p, float v) {
    unsafeAtomicAdd(p, v);
}

// K0: tiny precompute of folded vectors (GAT output is linear in h, so fold
// W_lin through W_out / att_src / att_dst once).
__global__ void k0_precompute(const float* __restrict__ Wlin,
                              const float* __restrict__ att_src,
                              const float* __restrict__ att_dst,
                              const float* __restrict__ Wedge,
                              const float* __restrict__ att_edge,
                              const float* __restrict__ bias_conv,
                              const float* __restrict__ Wout,
                              const float* __restrict__ bout,
                              float* __restrict__ vs, float* __restrict__ va,
                              float* __restrict__ vb, float* __restrict__ we,
                              float* __restrict__ cb) {
    int wid  = (blockIdx.x * blockDim.x + threadIdx.x) >> 6;
    int lane = threadIdx.x & 63;
    if (wid < 384) {
        int f = wid;
        float a = 0.f, b = 0.f, c = 0.f;
        for (int k = lane; k < 384; k += 64) {
            float w = Wlin[f * 384 + k];
            a += w * Wout[k];
            b += w * att_src[k];
            c += w * att_dst[k];
        }
        for (int off = 32; off > 0; off >>= 1) {
            a += __shfl_down(a, off);
            b += __shfl_down(b, off);
            c += __shfl_down(c, off);
        }
        if (lane == 0) { vs[f] = a; va[f] = b; vb[f] = c; }
    } else if (wid < 400) {
        int d = wid - 384;
        float a = 0.f;
        for (int k = lane; k < 384; k += 64) a += Wedge[d * 384 + k] * att_edge[k];
        for (int off = 32; off > 0; off >>= 1) a += __shfl_down(a, off);
        if (lane == 0) we[d] = a;
    } else if (wid == 400) {
        float a = 0.f;
        for (int k = lane; k < 384; k += 64) a += bias_conv[k] * Wout[k];
        for (int off = 32; off > 0; off >>= 1) a += __shfl_down(a, off);
        if (lane == 0) cb[0] = a + bout[0];
    }
}

// K1: one wave per node: s/asrc/adst dot products over the 384-wide row of x.
// Lane 0 also zero-inits the packed per-node accumulator float4.
__global__ void k1_node(const float* __restrict__ x,
                        const float* __restrict__ vs, const float* __restrict__ va,
                        const float* __restrict__ vb,
                        float* __restrict__ s, float* __restrict__ asrc,
                        float* __restrict__ adst, float4* __restrict__ acc,
                        int n_nodes) {
    int wid  = (blockIdx.x * blockDim.x + threadIdx.x) >> 6;
    int lane = threadIdx.x & 63;
    if (wid >= n_nodes) return;
    const float2* xr  = (const float2*)(x + (size_t)wid * 384);
    const float2* vs2 = (const float2*)vs;
    const float2* va2 = (const float2*)va;
    const float2* vb2 = (const float2*)vb;
    float a = 0.f, b = 0.f, c = 0.f;
#pragma unroll
    for (int k = 0; k < 3; ++k) {
        int idx = lane + 64 * k;
        float2 xv = xr[idx];
        float2 w1 = vs2[idx];
        float2 w2 = va2[idx];
        float2 w3 = vb2[idx];
        a += xv.x * w1.x + xv.y * w1.y;
        b += xv.x * w2.x + xv.y * w2.y;
        c += xv.x * w3.x + xv.y * w3.y;
    }
    for (int off = 32; off > 0; off >>= 1) {
        a += __shfl_down(a, off);
        b += __shfl_down(b, off);
        c += __shfl_down(c, off);
    }
    if (lane == 0) {
        s[wid] = a; asrc[wid] = b; adst[wid] = c;
        acc[wid] = make_float4(0.f, 0.f, 0.f, 0.f);  // deg, aesum, denom, num
    }
}

// K2: all per-edge work, one thread per edge, 4 native atomics into one
// contiguous float4 per dst node. No segment-max (logits |.| < ~25, raw exp
// is fp32-safe, softmax ratio unchanged).
__global__ void k2_edge(const float* __restrict__ ea, const int* __restrict__ src,
                        const int* __restrict__ dst, const float* __restrict__ we,
                        const float* __restrict__ asrc, const float* __restrict__ adst,
                        const float* __restrict__ s, float4* __restrict__ acc,
                        int n_edges) {
    int e = blockIdx.x * blockDim.x + threadIdx.x;
    if (e >= n_edges) return;
    const float4* r  = (const float4*)(ea + (size_t)e * 16);
    const float4* w4 = (const float4*)we;
    float a = 0.f;
#pragma unroll
    for (int j = 0; j < 4; ++j) {
        float4 v = r[j], w = w4[j];
        a += v.x * w.x + v.y * w.y + v.z * w.z + v.w * w.w;
    }
    int sn = src[e], dn = dst[e];
    float al = asrc[sn] + adst[dn] + a;
    al = al >= 0.f ? al : NEG_SLOPE * al;
    float ex = __expf(al);
    float* base = (float*)&acc[dn];
    atomAddF(base + 0, 1.0f);       // deg
    atomAddF(base + 1, a);          // aesum
    atomAddF(base + 2, ex);         // denom
    atomAddF(base + 3, ex * s[sn]); // num
}

// K3: fold in the self-loop term and produce the output:
//   al = leaky_relu(asrc+adst+aesum/max(deg,1)); ex = exp(al)
//   out = relu((num + ex*s)/(denom + ex) + cb)
__global__ void k3_out(const float* __restrict__ asrc, const float* __restrict__ adst,
                       const float4* __restrict__ acc, const float* __restrict__ s,
                       const float* __restrict__ cb, float* __restrict__ out,
                       int n_nodes) {
    int n = blockIdx.x * blockDim.x + threadIdx.x;
    if (n >= n_nodes) return;
    float4 ac = acc[n];                 // x=deg y=aesum z=denom w=num
    float d = ac.x < 1.f ? 1.f : ac.x;
    float al = asrc[n] + adst[n] + ac.y / d;
    al = al >= 0.f ? al : NEG_SLOPE * al;
    float ex = __expf(al);
    float v = (ac.w + ex * s[n]) / (ac.z + ex) + cb[0];
    out[n] = v > 0.f ? v : 0.f;
}

extern "C" void kernel_launch(void* const* d_in, const int* in_sizes, int n_in,
                              void* d_out, int out_size, void* d_ws, size_t ws_size,
                              hipStream_t stream) {
    const float* x        = (const float*)d_in[0];
    const int*   eidx     = (const int*)d_in[1];
    const float* ea       = (const float*)d_in[2];
    const float* Wlin     = (const float*)d_in[3];
    const float* att_src  = (const float*)d_in[4];
    const float* att_dst  = (const float*)d_in[5];
    const float* Wedge    = (const float*)d_in[6];
    const float* att_edge = (const float*)d_in[7];
    const float* bias_c   = (const float*)d_in[8];
    const float* Wout     = (const float*)d_in[9];
    const float* bout     = (const float*)d_in[10];
    float*       out      = (float*)d_out;

    const int N = in_sizes[0] / 384;   // 50000
    const int E = in_sizes[2] / 16;    // 200000
    const int* src = eidx;
    const int* dst = eidx + E;

    float* W = (float*)d_ws;
    float*  vs   = W;              // 384
    float*  va   = W + 384;        // 384
    float*  vb   = W + 768;        // 384
    float*  we   = W + 1152;       // 16
    float*  cb   = W + 1168;       // 1
    float*  s    = W + 1280;       // N
    float*  asrc = s + N;          // N
    float*  adst = asrc + N;       // N
    float4* acc  = (float4*)(adst + N);  // N float4 (16B-aligned: offset 1280+3N floats, N even)

    // K0: 401 waves of weight folding
    k0_precompute<<<(401 * 64 + 255) / 256, 256, 0, stream>>>(
        Wlin, att_src, att_dst, Wedge, att_edge, bias_c, Wout, bout,
        vs, va, vb, we, cb);
    // K1: one wave per node (dominant: 76.8 MB of x)
    k1_node<<<(N * 64 + 255) / 256, 256, 0, stream>>>(
        x, vs, va, vb, s, asrc, adst, acc, N);
    // K2: one thread per edge
    k2_edge<<<(E + 255) / 256, 256, 0, stream>>>(
        ea, src, dst, we, asrc, adst, s, acc, E);
    // K3: per-node epilogue
    k3_out<<<(N + 255) / 256, 256, 0, stream>>>(
        asrc, adst, acc, s, cb, out, N);
}